// Round 1
// baseline (241.880 us; speedup 1.0000x reference)
//
#include <hip/hip_runtime.h>
#include <math.h>

#define B_DIM 256
#define T_DIM 8192
#define BLOCK 256
#define NSLOT 256
#define K_PRED 4
#define NPB (BLOCK * K_PRED)            // 1024 pred float4 per block
#define NF4 (B_DIM * T_DIM * 3)         // 6,291,456 pred float4 total
#define NPH4 (NF4 / 4)                  // 1,572,864 phase float4 total
#define GRID_BLOCKS (NF4 / NPB)         // 6144 blocks -> 24 per CU exactly

// Design: thread-per-float4, all global loads unit-stride coalesced.
//  - sse/velsq/accsq elementwise via pred4[i], pred4[i+3], pred4[i+6] (L1-hot overlap)
//  - speed: per-f4 (local3, carry) pieces; carry exchanged to lane-1 via LDS (+1 sentinel)
//  - phase: f4-granular; (z,w) up-exchange and (argmax,max) down-exchange via LDS
//  - validity zeroed at producer (t==T-1) so consumers need no extra gating
// ws layout: NSLOT slots x 8 doubles: 0:sse+12*nll 1:coher_sum 2:coher_cnt 3:pen2 4:velsq 5:accsq

__device__ __forceinline__ unsigned div3u(unsigned x) {
    return __umulhi(x, 0xAAAAAAABu) >> 1;          // exact x/3 for all uint32
}
__device__ __forceinline__ float pen_term(float s) {
    float d = fmaxf(sqrtf(s) - 10.0f, 0.0f);
    return d * d;
}
__device__ __forceinline__ void argmax3(float l0, float l1, float l2, int &p, float &m) {
    p = 0; m = l0;
    if (l1 > m) { m = l1; p = 1; }
    if (l2 > m) { m = l2; p = 2; }
}
__device__ __forceinline__ float nll3(float l0, float l1, float l2, int g) {
    float mx = fmaxf(l0, fmaxf(l1, l2));
    float lse = mx + logf(expf(l0 - mx) + expf(l1 - mx) + expf(l2 - mx));
    float sel = (g == 0) ? l0 : ((g == 1) ? l1 : l2);
    return lse - sel;
}

__global__ __launch_bounds__(BLOCK) void combined_loss_main(
    const float4* __restrict__ pred4,
    const float4* __restrict__ ph4,
    const float4* __restrict__ gt4,
    const int*    __restrict__ gt_phase,
    double* __restrict__ ws)
{
    __shared__ float  s_carry[NPB + 1];     // carry per pred-f4 + next-block sentinel
    __shared__ float2 s_zw[BLOCK + 1];      // (z,w) of phase f4, shifted by +1; [0]=prev-block
    __shared__ float  s_pm_m[BLOCK + 1];    // primary-row max logit; [BLOCK]=next-block
    __shared__ int    s_pm_p[BLOCK + 1];    // primary-row argmax
    __shared__ float  s_red[4][6];

    const int tid = threadIdx.x;
    const int blk = blockIdx.x;
    const unsigned base = (unsigned)blk * NPB;

    float sse = 0.f, velsq = 0.f, accsq = 0.f;
    float loc[K_PRED], car[K_PRED];
    unsigned c0v = 0;

    // ---- pred path: unit-stride f4 loads, elementwise terms, speed pieces ----
    #pragma unroll
    for (int k = 0; k < K_PRED; ++k) {
        const unsigned i = base + (unsigned)(k * BLOCK) + tid;
        const unsigned r = div3u(i);
        const unsigned c = i - 3u * r;
        if (k == 0) c0v = c;
        const unsigned t = r & (T_DIM - 1);
        const bool v1 = t < (T_DIM - 1);
        const bool v2 = t < (T_DIM - 2);
        const unsigned i3 = v1 ? i + 3u : i;     // clamped: stays in-array, masked anyway
        const unsigned i6 = v2 ? i + 6u : i;

        const float4 A  = pred4[i];
        const float4 G  = gt4[i];
        const float4 A3 = pred4[i3];
        const float4 A6 = pred4[i6];

        float d;
        d = A.x - G.x; sse = fmaf(d, d, sse);
        d = A.y - G.y; sse = fmaf(d, d, sse);
        d = A.z - G.z; sse = fmaf(d, d, sse);
        d = A.w - G.w; sse = fmaf(d, d, sse);

        float sqx = 0.f, sqy = 0.f, sqz = 0.f, sqw = 0.f;
        if (v1) {
            const float vx = A3.x - A.x, vy = A3.y - A.y, vz = A3.z - A.z, vw = A3.w - A.w;
            sqx = vx * vx; sqy = vy * vy; sqz = vz * vz; sqw = vw * vw;
            velsq += sqx + sqy + sqz + sqw;
        }
        if (v2) {
            float a;
            a = A6.x - 2.0f * A3.x + A.x; accsq = fmaf(a, a, accsq);
            a = A6.y - 2.0f * A3.y + A.y; accsq = fmaf(a, a, accsq);
            a = A6.z - 2.0f * A3.z + A.z; accsq = fmaf(a, a, accsq);
            a = A6.w - 2.0f * A3.w + A.w; accsq = fmaf(a, a, accsq);
        }
        // speed pieces: s0=xyz(c0) s1=w(c0)+xy(c1) s2=zw(c1)+x(c2) s3=yzw(c2)
        float l3v, crv;
        if (c == 0)      { l3v = sqx + sqy + sqz; crv = sqw; }
        else if (c == 1) { l3v = sqz + sqw;       crv = sqx + sqy; }
        else             { l3v = sqy + sqz + sqw; crv = sqx; }
        loc[k] = l3v; car[k] = crv;
        s_carry[k * BLOCK + tid] = crv;
    }

    // ---- phase path, pre-barrier: own f4 + zw exchange ----
    const unsigned j = (unsigned)blk * BLOCK + tid;     // phase f4 index, 1 per thread
    const float4 P = ph4[j];
    s_zw[tid + 1] = make_float2(P.z, P.w);

    if (tid == 0) {
        // front sentinel: (z,w) of previous block's last phase f4
        float2 zwp = make_float2(0.f, 0.f);
        if (j != 0) {
            const float2* ph2 = (const float2*)ph4;
            zwp = ph2[2u * j - 1u];
        }
        s_zw[0] = zwp;
        // carry sentinel: carry of the first pred f4 of the next block
        float crs = 0.f;
        const unsigned ib = base + NPB;
        if (ib < (unsigned)NF4) {
            const unsigned rb = div3u(ib);
            const unsigned cb = ib - 3u * rb;
            const unsigned tb = rb & (T_DIM - 1);
            if (tb < (T_DIM - 1)) {
                const float4 Ab  = pred4[ib];
                const float4 Ab3 = pred4[ib + 3u];
                const float bx = Ab3.x - Ab.x, by = Ab3.y - Ab.y;
                const float bz = Ab3.z - Ab.z, bw = Ab3.w - Ab.w;
                const float sx = bx * bx, sy = by * by, sx2 = bz * bz, sw = bw * bw;
                (void)sx2;
                crs = (cb == 0) ? sw : ((cb == 1) ? (sx + sy) : sx);
            }
        }
        s_carry[NPB] = crs;
    }
    __syncthreads();    // barrier 1: carry + zw visible

    // ---- phase rows: nll + primary argmax ----
    const unsigned g   = div3u(j);
    const unsigned dph = j - 3u * g;
    const float2 zwp = s_zw[tid];
    float l0, l1, l2;
    if (dph == 0)      { l0 = P.x;   l1 = P.y;   l2 = P.z; }
    else if (dph == 1) { l0 = zwp.y; l1 = P.x;   l2 = P.y; }
    else               { l0 = zwp.x; l1 = zwp.y; l2 = P.x; }
    const unsigned prow = 4u * g + dph;

    int gA, gB = 0;
    if (dph == 2) {
        const int2 gg = ((const int2*)gt_phase)[prow >> 1];   // prow even for d2
        gA = gg.x; gB = gg.y;
    } else {
        gA = gt_phase[prow];
    }
    float nll = nll3(l0, l1, l2, gA);
    int pP; float mP;
    argmax3(l0, l1, l2, pP, mP);
    s_pm_m[tid] = mP; s_pm_p[tid] = pP;

    int p3 = 0; float m3 = 0.f;
    if (dph == 2) {                      // second, fully-local row (y,z,w)
        nll += nll3(P.y, P.z, P.w, gB);
        argmax3(P.y, P.z, P.w, p3, m3);
    }
    if (tid == BLOCK - 1) {
        // pm sentinel: primary (argmax,max) of next block's first phase f4
        float mS = 0.f; int pS = 0;
        const unsigned jn = j + 1u;
        if (jn < (unsigned)NPH4) {
            const float4 Pn = ph4[jn];
            const unsigned gn = div3u(jn);
            const unsigned dn = jn - 3u * gn;
            float a0, a1, a2;
            if (dn == 0)      { a0 = Pn.x; a1 = Pn.y; a2 = Pn.z; }
            else if (dn == 1) { a0 = P.w;  a1 = Pn.x; a2 = Pn.y; }
            else              { a0 = P.z;  a1 = P.w;  a2 = Pn.x; }
            argmax3(a0, a1, a2, pS, mS);
        }
        s_pm_m[BLOCK] = mS; s_pm_p[BLOCK] = pS;
    }
    __syncthreads();    // barrier 2: pm visible

    // ---- coherence pairs ----
    float csum = 0.f, ccnt = 0.f;
    {
        const float mN = s_pm_m[tid + 1];
        const int   pN = s_pm_p[tid + 1];
        const unsigned t1 = prow & (T_DIM - 1);
        if (t1 < (T_DIM - 1)) {                       // pair (prow, prow+1)
            const int   pB2 = (dph == 2) ? p3 : pN;
            const float mB2 = (dph == 2) ? m3 : mN;
            const int mask = (pP == 0) ? 4 : ((pP == 1) ? 1 : 3);
            if ((mask >> pB2) & 1) { csum += mB2 * mB2; ccnt += 1.f; }
        }
        if (dph == 2) {                               // pair (prow+1, prow+2)
            const unsigned t2 = (prow + 1u) & (T_DIM - 1);
            if (t2 < (T_DIM - 1)) {
                const int mask = (p3 == 0) ? 4 : ((p3 == 1) ? 1 : 3);
                if ((mask >> pN) & 1) { csum += mN * mN; ccnt += 1.f; }
            }
        }
    }

    // ---- speed: assemble per-row norms from local3 + neighbor carry ----
    float pen2 = 0.f;
    #pragma unroll
    for (int k = 0; k < K_PRED; ++k) {
        unsigned ck = c0v + (unsigned)k;              // (c0 + k) mod 3, c0+k <= 5
        if (ck >= 3u) ck -= 3u;
        const float up = s_carry[k * BLOCK + tid + 1];
        const float a = loc[k] + ((ck == 1u) ? up : 0.f);   // c0:s0  c1:s2  c2:s3
        const float b = (ck == 0u) ? (car[k] + up) : 0.f;   // c0:s1
        pen2 += pen_term(a) + pen_term(b);
    }

    // ---- reduce: 6 chains (sse+12*nll folded: /(B*T) == 12/(B*T*12)) ----
    float vals[6] = { fmaf(12.0f, nll, sse), csum, ccnt, pen2, velsq, accsq };
    #pragma unroll
    for (int off = 32; off > 0; off >>= 1) {
        #pragma unroll
        for (int q = 0; q < 6; ++q)
            vals[q] += __shfl_down(vals[q], off, 64);
    }
    const int wave = tid >> 6, lane = tid & 63;
    if (lane == 0) {
        #pragma unroll
        for (int q = 0; q < 6; ++q) s_red[wave][q] = vals[q];
    }
    __syncthreads();
    if (tid < 6) {
        const double acc = (double)s_red[0][tid] + (double)s_red[1][tid]
                         + (double)s_red[2][tid] + (double)s_red[3][tid];
        atomicAdd(&ws[(size_t)(blk & (NSLOT - 1)) * 8 + tid], acc);
    }
}

__global__ __launch_bounds__(256) void combined_loss_final(
    const double* __restrict__ ws, float* __restrict__ out)
{
    __shared__ double sred[4][6];
    const int tid = threadIdx.x;
    double v[6];
    #pragma unroll
    for (int q = 0; q < 6; ++q) v[q] = ws[(size_t)tid * 8 + q];
    #pragma unroll
    for (int off = 32; off > 0; off >>= 1) {
        #pragma unroll
        for (int q = 0; q < 6; ++q)
            v[q] += __shfl_down(v[q], off, 64);
    }
    const int wave = tid >> 6, lane = tid & 63;
    if (lane == 0) {
        #pragma unroll
        for (int q = 0; q < 6; ++q) sred[wave][q] = v[q];
    }
    __syncthreads();
    if (tid == 0) {
        double s[6];
        #pragma unroll
        for (int q = 0; q < 6; ++q)
            s[q] = sred[0][q] + sred[1][q] + sred[2][q] + sred[3][q];
        const double robot_phase = s[0] / (double)((size_t)B_DIM * T_DIM * 12);
        const double coher = (s[2] > 0.0) ? (s[1] / fmax(s[2], 1.0)) : 0.0;
        const double speed = 5.0  * (s[3] / (double)((size_t)B_DIM * (T_DIM - 1) * 4));
        const double vel   = 0.05 * (s[4] / (double)((size_t)B_DIM * (T_DIM - 1) * 12));
        const double acc   = 0.01 * (s[5] / (double)((size_t)B_DIM * (T_DIM - 2) * 12));
        out[0] = (float)(robot_phase + 10.0 * coher + speed + vel + acc);
    }
}

extern "C" void kernel_launch(void* const* d_in, const int* in_sizes, int n_in,
                              void* d_out, int out_size, void* d_ws, size_t ws_size,
                              hipStream_t stream)
{
    const float4* pred4      = (const float4*)d_in[0];
    const float4* ph4        = (const float4*)d_in[1];
    const float4* gt4        = (const float4*)d_in[2];
    const int*    gt_phase   = (const int*)d_in[3];
    double* ws  = (double*)d_ws;
    float*  out = (float*)d_out;

    hipMemsetAsync(d_ws, 0, (size_t)NSLOT * 8 * sizeof(double), stream);

    combined_loss_main<<<dim3(GRID_BLOCKS), BLOCK, 0, stream>>>(pred4, ph4, gt4, gt_phase, ws);
    combined_loss_final<<<1, 256, 0, stream>>>(ws, out);
}

// Round 2
// 239.434 us; speedup vs baseline: 1.0102x; 1.0102x over previous
//
#include <hip/hip_runtime.h>
#include <math.h>

#define B_DIM 256
#define T_DIM 8192
#define BLOCK 256
#define NSLOT 256
#define K_PRED 4
#define NPB (BLOCK * K_PRED)            // 1024 pred float4 per block
#define NF4 (B_DIM * T_DIM * 3)         // 6,291,456 pred float4 total
#define NPH4 (NF4 / 4)                  // 1,572,864 phase float4 total
#define GRID_BLOCKS (NF4 / NPB)         // 6144 blocks

// Thread-per-float4, unit-stride loads. This revision: MLP-first restructure.
//  - ALL global loads (16 pred/gt f4 + phase f4 + gt_phase + sentinels) issued
//    before any consumption -> ~17KB in flight per wave instead of ~2-4 loads.
//  - __launch_bounds__(BLOCK,3): register budget ~168 VGPR so loads stay batched.
//  - fast transcendentals (__expf/__logf -> v_exp_f32/v_log_f32).
// ws layout: NSLOT x 8 doubles: 0:sse+12*nll 1:coher_sum 2:coher_cnt 3:pen2 4:velsq 5:accsq

__device__ __forceinline__ unsigned div3u(unsigned x) {
    return __umulhi(x, 0xAAAAAAABu) >> 1;          // exact x/3 for all uint32
}
__device__ __forceinline__ float pen_term(float s) {
    float d = fmaxf(sqrtf(s) - 10.0f, 0.0f);
    return d * d;
}
__device__ __forceinline__ void argmax3(float l0, float l1, float l2, int &p, float &m) {
    p = 0; m = l0;
    if (l1 > m) { m = l1; p = 1; }
    if (l2 > m) { m = l2; p = 2; }
}
__device__ __forceinline__ float nll3(float l0, float l1, float l2, int g) {
    float mx = fmaxf(l0, fmaxf(l1, l2));
    float s = __expf(l0 - mx) + __expf(l1 - mx) + __expf(l2 - mx);
    float sel = (g == 0) ? l0 : ((g == 1) ? l1 : l2);
    return mx + __logf(s) - sel;
}

__global__ __launch_bounds__(BLOCK, 3) void combined_loss_main(
    const float4* __restrict__ pred4,
    const float4* __restrict__ ph4,
    const float4* __restrict__ gt4,
    const int*    __restrict__ gt_phase,
    double* __restrict__ ws)
{
    __shared__ float  s_carry[NPB + 1];     // carry per pred-f4 + next-block sentinel
    __shared__ float2 s_zw[BLOCK + 1];      // (z,w) of phase f4, shifted by +1; [0]=prev-block
    __shared__ float  s_pm_m[BLOCK + 1];    // primary-row max logit; [BLOCK]=next-block
    __shared__ int    s_pm_p[BLOCK + 1];    // primary-row argmax
    __shared__ float  s_red[4][6];

    const int tid = threadIdx.x;
    const int blk = blockIdx.x;
    const unsigned base = (unsigned)blk * NPB;
    const unsigned j = (unsigned)blk * BLOCK + tid;     // phase f4 index

    // ================= LOAD PHASE: issue everything up front =================

    // -- sentinel loads (divergent but issued first so the misses overlap) --
    float2 zwp_s = make_float2(0.f, 0.f);
    float4 Ab = make_float4(0.f,0.f,0.f,0.f), Ab3 = Ab;
    unsigned cb = 0; bool carry_sent = false;
    if (tid == 0) {
        if (j != 0) zwp_s = ((const float2*)ph4)[2u * j - 1u];
        const unsigned ib = base + NPB;
        if (ib < (unsigned)NF4) {
            const unsigned rb = div3u(ib);
            cb = ib - 3u * rb;
            if ((rb & (T_DIM - 1)) < (T_DIM - 1)) {
                carry_sent = true;
                Ab  = pred4[ib];
                Ab3 = pred4[ib + 3u];
            }
        }
    }
    float4 Pn = make_float4(0.f,0.f,0.f,0.f);
    bool pn_valid = false;
    if (tid == BLOCK - 1) {
        if (j + 1u < (unsigned)NPH4) { pn_valid = true; Pn = ph4[j + 1u]; }
    }

    // -- main pred/gt loads: 16 float4, all in flight --
    float4 A[K_PRED], G[K_PRED], A3[K_PRED], A6[K_PRED];
    unsigned cc[K_PRED];
    bool vv1[K_PRED], vv2[K_PRED];
    #pragma unroll
    for (int k = 0; k < K_PRED; ++k) {
        const unsigned i = base + (unsigned)(k * BLOCK) + tid;
        const unsigned r = div3u(i);
        cc[k] = i - 3u * r;
        const unsigned t = r & (T_DIM - 1);
        vv1[k] = t < (T_DIM - 1);
        vv2[k] = t < (T_DIM - 2);
        const unsigned ia = vv1[k] ? i + 3u : i;   // clamped: in-array, masked below
        const unsigned ic = vv2[k] ? i + 6u : i;
        A[k]  = pred4[i];
        G[k]  = gt4[i];
        A3[k] = pred4[ia];
        A6[k] = pred4[ic];
    }

    // -- phase f4 + gt labels --
    const float4 P = ph4[j];
    const unsigned g   = div3u(j);
    const unsigned dph = j - 3u * g;
    const unsigned prow = 4u * g + dph;
    int gA, gB = 0;
    if (dph == 2) {
        const int2 gg = ((const int2*)gt_phase)[prow >> 1];   // prow even for dph==2
        gA = gg.x; gB = gg.y;
    } else {
        gA = gt_phase[prow];
    }

    // ================= COMPUTE PHASE =================

    float sse = 0.f, velsq = 0.f, accsq = 0.f;
    float loc[K_PRED], car[K_PRED];
    #pragma unroll
    for (int k = 0; k < K_PRED; ++k) {
        float d;
        d = A[k].x - G[k].x; sse = fmaf(d, d, sse);
        d = A[k].y - G[k].y; sse = fmaf(d, d, sse);
        d = A[k].z - G[k].z; sse = fmaf(d, d, sse);
        d = A[k].w - G[k].w; sse = fmaf(d, d, sse);

        float sqx = 0.f, sqy = 0.f, sqz = 0.f, sqw = 0.f;
        if (vv1[k]) {
            const float vx = A3[k].x - A[k].x, vy = A3[k].y - A[k].y;
            const float vz = A3[k].z - A[k].z, vw = A3[k].w - A[k].w;
            sqx = vx * vx; sqy = vy * vy; sqz = vz * vz; sqw = vw * vw;
            velsq += sqx + sqy + sqz + sqw;
        }
        if (vv2[k]) {
            float a;
            a = A6[k].x - 2.0f * A3[k].x + A[k].x; accsq = fmaf(a, a, accsq);
            a = A6[k].y - 2.0f * A3[k].y + A[k].y; accsq = fmaf(a, a, accsq);
            a = A6[k].z - 2.0f * A3[k].z + A[k].z; accsq = fmaf(a, a, accsq);
            a = A6[k].w - 2.0f * A3[k].w + A[k].w; accsq = fmaf(a, a, accsq);
        }
        // speed pieces: s0=xyz(c0) s1=w(c0)+xy(c1) s2=zw(c1)+x(c2) s3=yzw(c2)
        float l3v, crv;
        const unsigned c = cc[k];
        if (c == 0)      { l3v = sqx + sqy + sqz; crv = sqw; }
        else if (c == 1) { l3v = sqz + sqw;       crv = sqx + sqy; }
        else             { l3v = sqy + sqz + sqw; crv = sqx; }
        loc[k] = l3v; car[k] = crv;
        s_carry[k * BLOCK + tid] = crv;
    }

    // -- LDS exchanges: zw + carry sentinel --
    s_zw[tid + 1] = make_float2(P.z, P.w);
    if (tid == 0) {
        s_zw[0] = zwp_s;
        float crs = 0.f;
        if (carry_sent) {
            const float bx = Ab3.x - Ab.x, by = Ab3.y - Ab.y;
            const float bz = Ab3.z - Ab.z, bw = Ab3.w - Ab.w;
            const float sx = bx * bx, sy = by * by, sw = bw * bw;
            (void)bz;
            crs = (cb == 0) ? sw : ((cb == 1) ? (sx + sy) : sx);
        }
        s_carry[NPB] = crs;
    }
    __syncthreads();    // barrier 1: carry + zw visible

    // -- phase rows: nll + primary argmax --
    const float2 zwp = s_zw[tid];
    float l0, l1, l2;
    if (dph == 0)      { l0 = P.x;   l1 = P.y;   l2 = P.z; }
    else if (dph == 1) { l0 = zwp.y; l1 = P.x;   l2 = P.y; }
    else               { l0 = zwp.x; l1 = zwp.y; l2 = P.x; }

    float nll = nll3(l0, l1, l2, gA);
    int pP; float mP;
    argmax3(l0, l1, l2, pP, mP);
    s_pm_m[tid] = mP; s_pm_p[tid] = pP;

    int p3 = 0; float m3 = 0.f;
    if (dph == 2) {                      // second, fully-local row (y,z,w)
        nll += nll3(P.y, P.z, P.w, gB);
        argmax3(P.y, P.z, P.w, p3, m3);
    }
    if (tid == BLOCK - 1) {
        // pm sentinel: primary (argmax,max) of next block's first phase f4
        float mS = 0.f; int pS = 0;
        if (pn_valid) {
            const unsigned jn = j + 1u;
            const unsigned gn = div3u(jn);
            const unsigned dn = jn - 3u * gn;
            float a0, a1, a2;
            if (dn == 0)      { a0 = Pn.x; a1 = Pn.y; a2 = Pn.z; }
            else if (dn == 1) { a0 = P.w;  a1 = Pn.x; a2 = Pn.y; }
            else              { a0 = P.z;  a1 = P.w;  a2 = Pn.x; }
            argmax3(a0, a1, a2, pS, mS);
        }
        s_pm_m[BLOCK] = mS; s_pm_p[BLOCK] = pS;
    }
    __syncthreads();    // barrier 2: pm visible

    // -- coherence pairs --
    float csum = 0.f, ccnt = 0.f;
    {
        const float mN = s_pm_m[tid + 1];
        const int   pN = s_pm_p[tid + 1];
        const unsigned t1 = prow & (T_DIM - 1);
        if (t1 < (T_DIM - 1)) {                       // pair (prow, prow+1)
            const int   pB2 = (dph == 2) ? p3 : pN;
            const float mB2 = (dph == 2) ? m3 : mN;
            const int mask = (pP == 0) ? 4 : ((pP == 1) ? 1 : 3);
            if ((mask >> pB2) & 1) { csum += mB2 * mB2; ccnt += 1.f; }
        }
        if (dph == 2) {                               // pair (prow+1, prow+2)
            const unsigned t2 = (prow + 1u) & (T_DIM - 1);
            if (t2 < (T_DIM - 1)) {
                const int mask = (p3 == 0) ? 4 : ((p3 == 1) ? 1 : 3);
                if ((mask >> pN) & 1) { csum += mN * mN; ccnt += 1.f; }
            }
        }
    }

    // -- speed: assemble per-row norms from local3 + neighbor carry --
    float pen2 = 0.f;
    #pragma unroll
    for (int k = 0; k < K_PRED; ++k) {
        unsigned ck = cc[k];
        const float up = s_carry[k * BLOCK + tid + 1];
        const float a = loc[k] + ((ck == 1u) ? up : 0.f);   // c0:s0  c1:s2  c2:s3
        const float b = (ck == 0u) ? (car[k] + up) : 0.f;   // c0:s1
        pen2 += pen_term(a) + pen_term(b);
    }

    // -- reduce: 6 chains (sse + 12*nll folded: /(B*T) == 12/(B*T*12)) --
    float vals[6] = { fmaf(12.0f, nll, sse), csum, ccnt, pen2, velsq, accsq };
    #pragma unroll
    for (int off = 32; off > 0; off >>= 1) {
        #pragma unroll
        for (int q = 0; q < 6; ++q)
            vals[q] += __shfl_down(vals[q], off, 64);
    }
    const int wave = tid >> 6, lane = tid & 63;
    if (lane == 0) {
        #pragma unroll
        for (int q = 0; q < 6; ++q) s_red[wave][q] = vals[q];
    }
    __syncthreads();
    if (tid < 6) {
        const double acc = (double)s_red[0][tid] + (double)s_red[1][tid]
                         + (double)s_red[2][tid] + (double)s_red[3][tid];
        atomicAdd(&ws[(size_t)(blk & (NSLOT - 1)) * 8 + tid], acc);
    }
}

__global__ __launch_bounds__(256) void combined_loss_final(
    const double* __restrict__ ws, float* __restrict__ out)
{
    __shared__ double sred[4][6];
    const int tid = threadIdx.x;
    double v[6];
    #pragma unroll
    for (int q = 0; q < 6; ++q) v[q] = ws[(size_t)tid * 8 + q];
    #pragma unroll
    for (int off = 32; off > 0; off >>= 1) {
        #pragma unroll
        for (int q = 0; q < 6; ++q)
            v[q] += __shfl_down(v[q], off, 64);
    }
    const int wave = tid >> 6, lane = tid & 63;
    if (lane == 0) {
        #pragma unroll
        for (int q = 0; q < 6; ++q) sred[wave][q] = v[q];
    }
    __syncthreads();
    if (tid == 0) {
        double s[6];
        #pragma unroll
        for (int q = 0; q < 6; ++q)
            s[q] = sred[0][q] + sred[1][q] + sred[2][q] + sred[3][q];
        const double robot_phase = s[0] / (double)((size_t)B_DIM * T_DIM * 12);
        const double coher = (s[2] > 0.0) ? (s[1] / fmax(s[2], 1.0)) : 0.0;
        const double speed = 5.0  * (s[3] / (double)((size_t)B_DIM * (T_DIM - 1) * 4));
        const double vel   = 0.05 * (s[4] / (double)((size_t)B_DIM * (T_DIM - 1) * 12));
        const double acc   = 0.01 * (s[5] / (double)((size_t)B_DIM * (T_DIM - 2) * 12));
        out[0] = (float)(robot_phase + 10.0 * coher + speed + vel + acc);
    }
}

extern "C" void kernel_launch(void* const* d_in, const int* in_sizes, int n_in,
                              void* d_out, int out_size, void* d_ws, size_t ws_size,
                              hipStream_t stream)
{
    const float4* pred4      = (const float4*)d_in[0];
    const float4* ph4        = (const float4*)d_in[1];
    const float4* gt4        = (const float4*)d_in[2];
    const int*    gt_phase   = (const int*)d_in[3];
    double* ws  = (double*)d_ws;
    float*  out = (float*)d_out;

    hipMemsetAsync(d_ws, 0, (size_t)NSLOT * 8 * sizeof(double), stream);

    combined_loss_main<<<dim3(GRID_BLOCKS), BLOCK, 0, stream>>>(pred4, ph4, gt4, gt_phase, ws);
    combined_loss_final<<<1, 256, 0, stream>>>(ws, out);
}